// Round 1
// 212.078 us; speedup vs baseline: 1.0026x; 1.0026x over previous
//
#include <hip/hip_runtime.h>
#include <hip/hip_fp16.h>

#define DMODEL 192
#define DINNER 384
#define NPOS   4096   // B*H*W = 4*32*32
#define SEQL   1024   // H*W
#define DSTATE 16
#define DTRANK 12
#define TILE   32     // k3 staging tile (positions)

__device__ __forceinline__ float silu_f(float v) { return v * (1.f / (1.f + __expf(-v))); }

__device__ __forceinline__ int scan_pos(int dir, int l) {
    int s = (dir & 1) ? (SEQL - 1 - l) : l;
    return (dir & 2) ? (((s & 31) << 5) | (s >> 5)) : s;
}

// ---------------------------------------------------------------------------
// K1: xz = x @ W_in. Wave-uniform x reads (scalar-load path), no LDS.
//     1536 blocks x 256 thr. (round-15 verified, unchanged)
// ---------------------------------------------------------------------------
__global__ void k1_inproj(const float* __restrict__ x, const float* __restrict__ W_in,
                          float* __restrict__ x_val, float* __restrict__ gz) {
    const int t = threadIdx.x;
    const int bi = blockIdx.x;
    const int colg = bi % 3;
    const int pos0 = (bi / 3) << 3;
    const int col = colg * 256 + t;

    const float* xr = x + pos0 * DMODEL;

    float acc[8] = {0,0,0,0,0,0,0,0};
    for (int c = 0; c < DMODEL; c += 4) {
        float w0 = W_in[(c + 0) * 768 + col];
        float w1 = W_in[(c + 1) * 768 + col];
        float w2 = W_in[(c + 2) * 768 + col];
        float w3 = W_in[(c + 3) * 768 + col];
#pragma unroll
        for (int g = 0; g < 8; ++g) {
            const float4 xv = *(const float4*)&xr[g * DMODEL + c];
            acc[g] += xv.x * w0 + xv.y * w1 + xv.z * w2 + xv.w * w3;
        }
    }
    if (col < DINNER) {
#pragma unroll
        for (int g = 0; g < 8; ++g) x_val[(pos0 + g) * DINNER + col] = acc[g];
    } else {
#pragma unroll
        for (int g = 0; g < 8; ++g) gz[(pos0 + g) * DINNER + (col - DINNER)] = silu_f(acc[g]);
    }
}

// ---------------------------------------------------------------------------
// K2: depthwise conv3x3 + bias + silu -> u (fp16) ; xd = u @ W_x (44 cols) ;
//     dt = softplus(b_dt + xd[:12] @ W_dt) ; y_acc init = 4*D*u.
//     NEW: B/C columns of xd stored INTERLEAVED (B_i -> 12+2i, C_i -> 13+2i)
//     so k3 can fetch (B,C) pairs with one ds_read_b64. xd has no other
//     consumer; dt part [0..12) unchanged.
// ---------------------------------------------------------------------------
__global__ void k2_conv_dt(const float* __restrict__ x_val,
                           const float* __restrict__ conv_w, const float* __restrict__ conv_b,
                           const float* __restrict__ W_x, const float* __restrict__ W_dt,
                           const float* __restrict__ b_dt, const float* __restrict__ Dp,
                           __half* __restrict__ u_out, float* __restrict__ xd_out,
                           float* __restrict__ dt32, float* __restrict__ y_acc) {
    __shared__ float us[DINNER];
    __shared__ float part[8 * 44];
    __shared__ float xdl[44];
    const int t = threadIdx.x;
    const int pos = blockIdx.x;
    const int b = pos >> 10, hw = pos & 1023, h = hw >> 5, w = hw & 31;

    float acc = conv_b[t];
#pragma unroll
    for (int i = 0; i < 3; ++i) {
        int hh = h + i - 1;
        if (hh < 0 || hh > 31) continue;
#pragma unroll
        for (int j = 0; j < 3; ++j) {
            int ww = w + j - 1;
            if (ww < 0 || ww > 31) continue;
            acc += x_val[((b * 32 + hh) * 32 + ww) * DINNER + t] * conv_w[t * 9 + i * 3 + j];
        }
    }
    float uv = silu_f(acc);
    us[t] = uv;
    u_out[pos * DINNER + t] = __float2half(uv);
    __syncthreads();

    if (t < 352) {
        int o = t % 44, p = t / 44;
        float s = 0.f;
        int j0 = p * 48;
        for (int j = j0; j < j0 + 48; ++j) s += us[j] * W_x[j * 44 + o];
        part[p * 44 + o] = s;
    }
    __syncthreads();
    if (t < 44) {
        float s = 0.f;
#pragma unroll
        for (int p = 0; p < 8; ++p) s += part[p * 44 + t];
        int o;
        if (t < DTRANK)               o = t;                                   // dt part
        else if (t < DTRANK + DSTATE) o = DTRANK + 2 * (t - DTRANK);           // B_i
        else                          o = DTRANK + 1 + 2 * (t - DTRANK - DSTATE); // C_i
        xd_out[pos * 48 + o] = s;
        xdl[t] = s;
    }
    __syncthreads();

    float raw = b_dt[t];
#pragma unroll
    for (int r = 0; r < DTRANK; ++r) raw += xdl[r] * W_dt[r * DINNER + t];
    dt32[pos * DINNER + t] = fmaxf(raw, 0.f) + log1pf(__expf(-fabsf(raw)));

    y_acc[pos * DINNER + t] = 4.f * Dp[t] * uv;
}

// ---------------------------------------------------------------------------
// K3 v2: LDS double-buffered scan.
//   Theory (this round): 52-VGPR binary re-serialized the register prefetch;
//   per-thread strided gathers (stride 1536B) exposed ~L2 latency on the
//   serial scan chain at 1.5 waves/SIMD (VALUBusy 25%, occupancy 10.7%).
//   Fix: stage dt/BC/u tiles (32 pos) into LDS with global_load_lds
//   (width 16, zero VGPR cost), double-buffered; the __syncthreads vmcnt
//   drain overlaps next tile's loads with current tile's compute.
//   Scan arithmetic is bit-identical to round-15 (same chains, same shfl
//   butterfly, same atomics); block-level early-exit — dead waves keep
//   staging but skip compute (their contributions are exact zeros, same
//   as the reference's decay-underflow semantics).
// ---------------------------------------------------------------------------
__device__ __forceinline__ void gll16(const void* g, void* l) {
    __builtin_amdgcn_global_load_lds(
        (const __attribute__((address_space(1))) void*)g,
        (__attribute__((address_space(3))) void*)l, 16, 0, 0);
}

// Stage one tile (TILE=32 positions) for this block into LDS buffers.
// 7 global_load_lds_dwordx4 total per tile, split across the 4 waves:
//   wv0: dt  (2 instr, 16 pos each)        dt_d [32][16] f32
//   wv1: BC  pos  0..15 (2 instr, 8 pos)   bc_d [32][32] f32 (B,C interleaved)
//   wv2: BC  pos 16..31 (2 instr)
//   wv3: u   (1 instr, all 32 pos)         u_d  [32][16] f16
__device__ __forceinline__ void k3_stage(int l0, int dir, int d0, int wv, int lane,
                                         const float* __restrict__ dtb,
                                         const float* __restrict__ xb,
                                         const __half* __restrict__ ub,
                                         float* dt_d, float* bc_d, __half* u_d) {
    if (wv == 0) {
#pragma unroll
        for (int s = 0; s < 2; ++s) {
            int j = s * 16 + (lane >> 2);
            int pos = scan_pos(dir, l0 + j);
            gll16(dtb + pos * DINNER + d0 + (lane & 3) * 4, dt_d + s * 16 * 16);
        }
    } else if (wv == 3) {
        int pos = scan_pos(dir, l0 + (lane >> 1));
        gll16((const char*)ub + (size_t)(pos * DINNER + d0) * 2 + (lane & 1) * 16, u_d);
    } else {
        int jb0 = (wv - 1) * 16;
#pragma unroll
        for (int s = 0; s < 2; ++s) {
            int jb = jb0 + s * 8;
            int pos = scan_pos(dir, l0 + jb + (lane >> 3));
            gll16(xb + pos * 48 + DTRANK + (lane & 7) * 4, bc_d + jb * 32);
        }
    }
}

// One chunk of 8 positions, data from LDS. Arithmetic order identical to
// round-15 k3_compute (same absmax).
__device__ __forceinline__ bool k3_chunk(float A, float& cum, float& S,
                                         const float* __restrict__ dt_s,
                                         const float* __restrict__ bc_s,
                                         const __half* __restrict__ u_s,
                                         int jb, int l0, int dir, int dl, int n,
                                         float* __restrict__ yb, int d) {
    float dtv[8], Bv[8], Cv[8], uv[8];
#pragma unroll
    for (int k = 0; k < 8; ++k) {
        dtv[k] = dt_s[(jb + k) * 16 + dl];
        Bv[k]  = bc_s[(jb + k) * 32 + 2 * n];
        Cv[k]  = bc_s[(jb + k) * 32 + 2 * n + 1];
        uv[k]  = __half2float(u_s[(jb + k) * 16 + dl]);
    }
    float decay[8];
#pragma unroll
    for (int k = 0; k < 8; ++k) { cum += dtv[k] * A; decay[k] = __expf(cum); }
    float rc[8];
#pragma unroll
    for (int k = 0; k < 8; ++k) rc[k] = __builtin_amdgcn_rcpf(decay[k] + 1e-12f);
    float c[8];
#pragma unroll
    for (int k = 0; k < 8; ++k) {
        S += (dtv[k] * Bv[k] * uv[k]) * rc[k];
        c[k] = decay[k] * S * Cv[k];
    }
#pragma unroll
    for (int off = 1; off <= 8; off <<= 1) {
#pragma unroll
        for (int k = 0; k < 8; ++k) c[k] += __shfl_xor(c[k], off);
    }
    if (n == 0) {
#pragma unroll
        for (int k = 0; k < 8; ++k) {
            int pos = scan_pos(dir, l0 + jb + k);
            atomicAdd(&yb[pos * DINNER + d], c[k]);
        }
    }
    return __ballot(cum > -110.f) != 0ull;       // wave alive?
}

__global__ void __launch_bounds__(256, 1)
k3_scan(const __half* __restrict__ u, const float* __restrict__ xd,
        const float* __restrict__ dt32, const float* __restrict__ A_log,
        float* __restrict__ y_acc) {
    __shared__ float  dt_s[2][TILE * 16];
    __shared__ float  BC_s[2][TILE * 32];
    __shared__ __half u_s [2][TILE * 16];
    __shared__ int    alive_w[2][4];             // parity-buffered: no flag race

    const int t = threadIdx.x;
    const int lane = t & 63, wv = t >> 6;
    const int n = t & 15, dl = t >> 4;
    const int bi = blockIdx.x;
    const int chunk = bi % 24;
    const int b = (bi / 24) % 4;
    const int dir = bi / 96;
    const int d0 = chunk * 16, d = d0 + dl;

    const float A = -__expf(A_log[d * DSTATE + n]);

    const __half* ub  = u    + b * SEQL * DINNER;
    const float* xb   = xd   + b * SEQL * 48;
    const float* dtb  = dt32 + b * SEQL * DINNER;
    float* yb = y_acc + b * SEQL * DINNER;

    k3_stage(0, dir, d0, wv, lane, dtb, xb, ub, dt_s[0], BC_s[0], u_s[0]);
    __syncthreads();                              // vmcnt drain: tile 0 landed

    float cum = 0.f, S = 0.f;
    bool alive = true;
    int buf = 0, par = 0;
    for (int l0 = 0; l0 < SEQL; l0 += TILE) {
        const int ln = (l0 + TILE < SEQL) ? (l0 + TILE) : l0;  // tail restage harmless
        k3_stage(ln, dir, d0, wv, lane, dtb, xb, ub,
                 dt_s[buf ^ 1], BC_s[buf ^ 1], u_s[buf ^ 1]);
        if (alive) {
#pragma unroll
            for (int jb = 0; jb < TILE; jb += 8) {
                alive = k3_chunk(A, cum, S, dt_s[buf], BC_s[buf], u_s[buf],
                                 jb, l0, dir, dl, n, yb, d);
                if (!alive) break;
            }
        }
        if (lane == 0) alive_w[par][wv] = alive ? 1 : 0;
        __syncthreads();                          // drains next-tile gll + flags
        const int any = alive_w[par][0] | alive_w[par][1] | alive_w[par][2] | alive_w[par][3];
        buf ^= 1; par ^= 1;
        if (!any) return;                         // block-level early exit
    }
}

// ---------------------------------------------------------------------------
// K4: LayerNorm + gate + out-proj. 512 blocks x 384 thr, 8 pos/block.
//     (round-14 verified, unchanged)
// ---------------------------------------------------------------------------
__global__ void k4_out(const float* __restrict__ y_acc, const float* __restrict__ gz,
                       const float* __restrict__ gamma, const float* __restrict__ beta,
                       const float* __restrict__ W_out, float* __restrict__ out) {
    __shared__ float g_s[8 * DINNER];
    __shared__ float red[12];
    const int t = threadIdx.x;
    const int half = t / 192, tc = t % 192;
    const int lane = t & 63, wv = t >> 6;
    const int pos0 = blockIdx.x << 3;

    const float g0c = gamma[tc], g1c = gamma[tc + 192];
    const float b0c = beta[tc],  b1c = beta[tc + 192];

    for (int it = 0; it < 4; ++it) {
        int p = it * 2 + half;
        int pos = pos0 + p;
        float y0 = y_acc[pos * DINNER + tc];
        float y1 = y_acc[pos * DINNER + tc + 192];

        float s = y0 + y1;
#pragma unroll
        for (int off = 32; off > 0; off >>= 1) s += __shfl_xor(s, off);
        if (lane == 0) red[wv] = s;
        __syncthreads();
        float mu = (red[half * 3] + red[half * 3 + 1] + red[half * 3 + 2]) * (1.f / 384.f);

        float d0 = y0 - mu, d1 = y1 - mu;
        float sq = d0 * d0 + d1 * d1;
#pragma unroll
        for (int off = 32; off > 0; off >>= 1) sq += __shfl_xor(sq, off);
        if (lane == 0) red[6 + wv] = sq;
        __syncthreads();
        float var = (red[6 + half * 3] + red[6 + half * 3 + 1] + red[6 + half * 3 + 2]) * (1.f / 384.f);
        float inv = rsqrtf(var + 1e-5f);

        g_s[p * DINNER + tc]       = (d0 * inv * g0c + b0c) * gz[pos * DINNER + tc];
        g_s[p * DINNER + tc + 192] = (d1 * inv * g1c + b1c) * gz[pos * DINNER + tc + 192];
    }
    __syncthreads();

    float acc[4] = {0.f, 0.f, 0.f, 0.f};
    const int pbase = half * 4;
    for (int dd = 0; dd < DINNER; dd += 4) {
        float w0 = W_out[(dd + 0) * DMODEL + tc];
        float w1 = W_out[(dd + 1) * DMODEL + tc];
        float w2 = W_out[(dd + 2) * DMODEL + tc];
        float w3 = W_out[(dd + 3) * DMODEL + tc];
#pragma unroll
        for (int i = 0; i < 4; ++i) {
            const float4 g = *(const float4*)&g_s[(pbase + i) * DINNER + dd];
            acc[i] += g.x * w0 + g.y * w1 + g.z * w2 + g.w * w3;
        }
    }
#pragma unroll
    for (int i = 0; i < 4; ++i) out[(pos0 + pbase + i) * DMODEL + tc] = acc[i];
}

// ---------------------------------------------------------------------------
extern "C" void kernel_launch(void* const* d_in, const int* in_sizes, int n_in,
                              void* d_out, int out_size, void* d_ws, size_t ws_size,
                              hipStream_t stream) {
    (void)in_sizes; (void)n_in; (void)out_size; (void)ws_size;
    const float* x      = (const float*)d_in[0];
    const float* W_in   = (const float*)d_in[1];
    const float* conv_w = (const float*)d_in[2];
    const float* conv_b = (const float*)d_in[3];
    const float* W_x    = (const float*)d_in[4];
    const float* W_dt   = (const float*)d_in[5];
    const float* b_dt   = (const float*)d_in[6];
    const float* A_log  = (const float*)d_in[7];
    const float* Dp     = (const float*)d_in[8];
    const float* W_out  = (const float*)d_in[9];
    const float* gamma  = (const float*)d_in[10];
    const float* beta   = (const float*)d_in[11];

    // ws layout (27.75 MB, verified):
    //  x_val fp32 : 6 MB    @ 0
    //  u     fp16 : 3 MB    @ 6291456
    //  xd    fp32 : 0.75 MB @ 9437184   (B/C interleaved layout, k3-private)
    //  dt32  fp32 : 6 MB    @ 10223616
    //  gz    fp32 : 6 MB    @ 16515072
    //  y_acc fp32 : 6 MB    @ 22806528  (SEPARATE from x_val: no halo race)
    char* base = (char*)d_ws;
    float*  x_val = (float*)base;
    __half* u     = (__half*)(base + 6291456);
    float*  xd    = (float*)(base + 9437184);
    float*  dt32  = (float*)(base + 10223616);
    float*  gz    = (float*)(base + 16515072);
    float*  y_acc = (float*)(base + 22806528);

    hipLaunchKernelGGL(k1_inproj, dim3(NPOS / 8 * 3), dim3(256), 0, stream, x, W_in, x_val, gz);
    hipLaunchKernelGGL(k2_conv_dt, dim3(NPOS), dim3(384), 0, stream,
                       x_val, conv_w, conv_b, W_x, W_dt, b_dt, Dp, u, xd, dt32, y_acc);
    hipLaunchKernelGGL(k3_scan, dim3(384), dim3(256), 0, stream,
                       u, xd, dt32, A_log, y_acc);
    hipLaunchKernelGGL(k4_out, dim3(NPOS / 8), dim3(384), 0, stream,
                       y_acc, gz, gamma, beta, W_out, (float*)d_out);
}

// Round 2
// 203.695 us; speedup vs baseline: 1.0438x; 1.0412x over previous
//
#include <hip/hip_runtime.h>
#include <hip/hip_fp16.h>

#define DMODEL 192
#define DINNER 384
#define NPOS   4096   // B*H*W = 4*32*32
#define SEQL   1024   // H*W
#define DSTATE 16
#define DTRANK 12
#define TILE   32     // k3 staging tile (positions)

__device__ __forceinline__ float silu_f(float v) { return v * (1.f / (1.f + __expf(-v))); }

__device__ __forceinline__ int scan_pos(int dir, int l) {
    int s = (dir & 1) ? (SEQL - 1 - l) : l;
    return (dir & 2) ? (((s & 31) << 5) | (s >> 5)) : s;
}

// DPP lane-move within the 16-lane row (n-group). CTRL: 0xB1=quad_perm xor1,
// 0x4E=quad_perm xor2, 0x124=row_ror:4, 0x128=row_ror:8.
template<int CTRL>
__device__ __forceinline__ float dpp_mov(float v) {
    return __int_as_float(__builtin_amdgcn_update_dpp(
        0, __float_as_int(v), CTRL, 0xF, 0xF, true));
}

// ---------------------------------------------------------------------------
// K1: xz = x @ W_in. Wave-uniform x reads (scalar-load path), no LDS.
//     1536 blocks x 256 thr. (round-15 verified, unchanged)
// ---------------------------------------------------------------------------
__global__ void k1_inproj(const float* __restrict__ x, const float* __restrict__ W_in,
                          float* __restrict__ x_val, float* __restrict__ gz) {
    const int t = threadIdx.x;
    const int bi = blockIdx.x;
    const int colg = bi % 3;
    const int pos0 = (bi / 3) << 3;
    const int col = colg * 256 + t;

    const float* xr = x + pos0 * DMODEL;

    float acc[8] = {0,0,0,0,0,0,0,0};
    for (int c = 0; c < DMODEL; c += 4) {
        float w0 = W_in[(c + 0) * 768 + col];
        float w1 = W_in[(c + 1) * 768 + col];
        float w2 = W_in[(c + 2) * 768 + col];
        float w3 = W_in[(c + 3) * 768 + col];
#pragma unroll
        for (int g = 0; g < 8; ++g) {
            const float4 xv = *(const float4*)&xr[g * DMODEL + c];
            acc[g] += xv.x * w0 + xv.y * w1 + xv.z * w2 + xv.w * w3;
        }
    }
    if (col < DINNER) {
#pragma unroll
        for (int g = 0; g < 8; ++g) x_val[(pos0 + g) * DINNER + col] = acc[g];
    } else {
#pragma unroll
        for (int g = 0; g < 8; ++g) gz[(pos0 + g) * DINNER + (col - DINNER)] = silu_f(acc[g]);
    }
}

// ---------------------------------------------------------------------------
// K2: depthwise conv3x3 + bias + silu -> u (fp16) ; xd = u @ W_x (44 cols) ;
//     dt = softplus(b_dt + xd[:12] @ W_dt) ; y_acc init = 4*D*u.
//     B/C columns of xd stored INTERLEAVED (B_i -> 12+2i, C_i -> 13+2i)
//     so k3 can fetch (B,C) pairs with one ds_read_b64. (round-1 verified)
// ---------------------------------------------------------------------------
__global__ void k2_conv_dt(const float* __restrict__ x_val,
                           const float* __restrict__ conv_w, const float* __restrict__ conv_b,
                           const float* __restrict__ W_x, const float* __restrict__ W_dt,
                           const float* __restrict__ b_dt, const float* __restrict__ Dp,
                           __half* __restrict__ u_out, float* __restrict__ xd_out,
                           float* __restrict__ dt32, float* __restrict__ y_acc) {
    __shared__ float us[DINNER];
    __shared__ float part[8 * 44];
    __shared__ float xdl[44];
    const int t = threadIdx.x;
    const int pos = blockIdx.x;
    const int b = pos >> 10, hw = pos & 1023, h = hw >> 5, w = hw & 31;

    float acc = conv_b[t];
#pragma unroll
    for (int i = 0; i < 3; ++i) {
        int hh = h + i - 1;
        if (hh < 0 || hh > 31) continue;
#pragma unroll
        for (int j = 0; j < 3; ++j) {
            int ww = w + j - 1;
            if (ww < 0 || ww > 31) continue;
            acc += x_val[((b * 32 + hh) * 32 + ww) * DINNER + t] * conv_w[t * 9 + i * 3 + j];
        }
    }
    float uv = silu_f(acc);
    us[t] = uv;
    u_out[pos * DINNER + t] = __float2half(uv);
    __syncthreads();

    if (t < 352) {
        int o = t % 44, p = t / 44;
        float s = 0.f;
        int j0 = p * 48;
        for (int j = j0; j < j0 + 48; ++j) s += us[j] * W_x[j * 44 + o];
        part[p * 44 + o] = s;
    }
    __syncthreads();
    if (t < 44) {
        float s = 0.f;
#pragma unroll
        for (int p = 0; p < 8; ++p) s += part[p * 44 + t];
        int o;
        if (t < DTRANK)               o = t;                                   // dt part
        else if (t < DTRANK + DSTATE) o = DTRANK + 2 * (t - DTRANK);           // B_i
        else                          o = DTRANK + 1 + 2 * (t - DTRANK - DSTATE); // C_i
        xd_out[pos * 48 + o] = s;
        xdl[t] = s;
    }
    __syncthreads();

    float raw = b_dt[t];
#pragma unroll
    for (int r = 0; r < DTRANK; ++r) raw += xdl[r] * W_dt[r * DINNER + t];
    dt32[pos * DINNER + t] = fmaxf(raw, 0.f) + log1pf(__expf(-fabsf(raw)));

    y_acc[pos * DINNER + t] = 4.f * Dp[t] * uv;
}

// ---------------------------------------------------------------------------
// K3 v3: LDS double-buffered scan (round-1 structure) + straggler issue-cost
//   reduction. Round-1 post-mortem: staging was neutral -> k3 is bound by the
//   per-position ISSUE cost of the straggler wave (~100 cyc/pos x ~1024 pos).
//   This round cuts the two biggest non-essential issue items:
//   (1) shfl-xor butterfly (4x ds_bpermute, ~24 cyc/pos) -> DPP rotate
//       reduction within the 16-lane row (~8 cyc/pos, VALU pipe, no lgkm).
//   (2) exp -> exp2 domain: A pre-scaled by log2(e); decay = exp2(cum) is a
//       bare v_exp_f32 (drops one v_mul per step). Alive threshold -158.7
//       (= -110 * log2e). Guard rc = rcp(decay+1e-12) unchanged.
// ---------------------------------------------------------------------------
__device__ __forceinline__ void gll16(const void* g, void* l) {
    __builtin_amdgcn_global_load_lds(
        (const __attribute__((address_space(1))) void*)g,
        (__attribute__((address_space(3))) void*)l, 16, 0, 0);
}

// Stage one tile (TILE=32 positions) for this block into LDS buffers.
// 7 global_load_lds_dwordx4 total per tile, split across the 4 waves.
__device__ __forceinline__ void k3_stage(int l0, int dir, int d0, int wv, int lane,
                                         const float* __restrict__ dtb,
                                         const float* __restrict__ xb,
                                         const __half* __restrict__ ub,
                                         float* dt_d, float* bc_d, __half* u_d) {
    if (wv == 0) {
#pragma unroll
        for (int s = 0; s < 2; ++s) {
            int j = s * 16 + (lane >> 2);
            int pos = scan_pos(dir, l0 + j);
            gll16(dtb + pos * DINNER + d0 + (lane & 3) * 4, dt_d + s * 16 * 16);
        }
    } else if (wv == 3) {
        int pos = scan_pos(dir, l0 + (lane >> 1));
        gll16((const char*)ub + (size_t)(pos * DINNER + d0) * 2 + (lane & 1) * 16, u_d);
    } else {
        int jb0 = (wv - 1) * 16;
#pragma unroll
        for (int s = 0; s < 2; ++s) {
            int jb = jb0 + s * 8;
            int pos = scan_pos(dir, l0 + jb + (lane >> 3));
            gll16(xb + pos * 48 + DTRANK + (lane & 7) * 4, bc_d + jb * 32);
        }
    }
}

// One chunk of 8 positions, data from LDS. Same arithmetic as round-1 except
// exp2 domain (A pre-scaled) and DPP reduction (sum order within the 16-term
// n-reduction changes; fp noise ~1e-7, far under tolerance).
__device__ __forceinline__ bool k3_chunk(float A, float& cum, float& S,
                                         const float* __restrict__ dt_s,
                                         const float* __restrict__ bc_s,
                                         const __half* __restrict__ u_s,
                                         int jb, int l0, int dir, int dl, int n,
                                         float* __restrict__ yb, int d) {
    float dtv[8], Bv[8], Cv[8], uv[8];
#pragma unroll
    for (int k = 0; k < 8; ++k) {
        dtv[k] = dt_s[(jb + k) * 16 + dl];
        Bv[k]  = bc_s[(jb + k) * 32 + 2 * n];
        Cv[k]  = bc_s[(jb + k) * 32 + 2 * n + 1];
        uv[k]  = __half2float(u_s[(jb + k) * 16 + dl]);
    }
    float decay[8];
#pragma unroll
    for (int k = 0; k < 8; ++k) { cum += dtv[k] * A; decay[k] = __builtin_amdgcn_exp2f(cum); }
    float rc[8];
#pragma unroll
    for (int k = 0; k < 8; ++k) rc[k] = __builtin_amdgcn_rcpf(decay[k] + 1e-12f);
    float c[8];
#pragma unroll
    for (int k = 0; k < 8; ++k) {
        S += (dtv[k] * Bv[k] * uv[k]) * rc[k];
        c[k] = decay[k] * S * Cv[k];
    }
    // DPP rotate-reduction over the 16-lane n-row (replaces ds_bpermute
    // butterfly): quad xor1, quad xor2, then row_ror 4 and 8. Every lane of
    // the row ends with the row total; only n==0 lanes consume it.
#pragma unroll
    for (int k = 0; k < 8; ++k) {
        float v = c[k];
        v += dpp_mov<0xB1>(v);    // quad_perm [1,0,3,2]  (xor 1)
        v += dpp_mov<0x4E>(v);    // quad_perm [2,3,0,1]  (xor 2)
        v += dpp_mov<0x124>(v);   // row_ror:4
        v += dpp_mov<0x128>(v);   // row_ror:8
        c[k] = v;
    }
    if (n == 0) {
#pragma unroll
        for (int k = 0; k < 8; ++k) {
            int pos = scan_pos(dir, l0 + jb + k);
            atomicAdd(&yb[pos * DINNER + d], c[k]);
        }
    }
    return __ballot(cum > -158.7f) != 0ull;      // wave alive? (log2 domain)
}

__global__ void __launch_bounds__(256, 1)
k3_scan(const __half* __restrict__ u, const float* __restrict__ xd,
        const float* __restrict__ dt32, const float* __restrict__ A_log,
        float* __restrict__ y_acc) {
    __shared__ float  dt_s[2][TILE * 16];
    __shared__ float  BC_s[2][TILE * 32];
    __shared__ __half u_s [2][TILE * 16];
    __shared__ int    alive_w[2][4];             // parity-buffered: no flag race

    const int t = threadIdx.x;
    const int lane = t & 63, wv = t >> 6;
    const int n = t & 15, dl = t >> 4;
    const int bi = blockIdx.x;
    const int chunk = bi % 24;
    const int b = (bi / 24) % 4;
    const int dir = bi / 96;
    const int d0 = chunk * 16, d = d0 + dl;

    // log2-domain A: cum accumulates dt*A*log2(e); decay = exp2(cum).
    const float A = -__expf(A_log[d * DSTATE + n]) * 1.4426950408889634f;

    const __half* ub  = u    + b * SEQL * DINNER;
    const float* xb   = xd   + b * SEQL * 48;
    const float* dtb  = dt32 + b * SEQL * DINNER;
    float* yb = y_acc + b * SEQL * DINNER;

    k3_stage(0, dir, d0, wv, lane, dtb, xb, ub, dt_s[0], BC_s[0], u_s[0]);
    __syncthreads();                              // vmcnt drain: tile 0 landed

    float cum = 0.f, S = 0.f;
    bool alive = true;
    int buf = 0, par = 0;
    for (int l0 = 0; l0 < SEQL; l0 += TILE) {
        const int ln = (l0 + TILE < SEQL) ? (l0 + TILE) : l0;  // tail restage harmless
        k3_stage(ln, dir, d0, wv, lane, dtb, xb, ub,
                 dt_s[buf ^ 1], BC_s[buf ^ 1], u_s[buf ^ 1]);
        if (alive) {
#pragma unroll
            for (int jb = 0; jb < TILE; jb += 8) {
                alive = k3_chunk(A, cum, S, dt_s[buf], BC_s[buf], u_s[buf],
                                 jb, l0, dir, dl, n, yb, d);
                if (!alive) break;
            }
        }
        if (lane == 0) alive_w[par][wv] = alive ? 1 : 0;
        __syncthreads();                          // drains next-tile gll + flags
        const int any = alive_w[par][0] | alive_w[par][1] | alive_w[par][2] | alive_w[par][3];
        buf ^= 1; par ^= 1;
        if (!any) return;                         // block-level early exit
    }
}

// ---------------------------------------------------------------------------
// K4: LayerNorm + gate + out-proj. 512 blocks x 384 thr, 8 pos/block.
//     (round-14 verified, unchanged)
// ---------------------------------------------------------------------------
__global__ void k4_out(const float* __restrict__ y_acc, const float* __restrict__ gz,
                       const float* __restrict__ gamma, const float* __restrict__ beta,
                       const float* __restrict__ W_out, float* __restrict__ out) {
    __shared__ float g_s[8 * DINNER];
    __shared__ float red[12];
    const int t = threadIdx.x;
    const int half = t / 192, tc = t % 192;
    const int lane = t & 63, wv = t >> 6;
    const int pos0 = blockIdx.x << 3;

    const float g0c = gamma[tc], g1c = gamma[tc + 192];
    const float b0c = beta[tc],  b1c = beta[tc + 192];

    for (int it = 0; it < 4; ++it) {
        int p = it * 2 + half;
        int pos = pos0 + p;
        float y0 = y_acc[pos * DINNER + tc];
        float y1 = y_acc[pos * DINNER + tc + 192];

        float s = y0 + y1;
#pragma unroll
        for (int off = 32; off > 0; off >>= 1) s += __shfl_xor(s, off);
        if (lane == 0) red[wv] = s;
        __syncthreads();
        float mu = (red[half * 3] + red[half * 3 + 1] + red[half * 3 + 2]) * (1.f / 384.f);

        float d0 = y0 - mu, d1 = y1 - mu;
        float sq = d0 * d0 + d1 * d1;
#pragma unroll
        for (int off = 32; off > 0; off >>= 1) sq += __shfl_xor(sq, off);
        if (lane == 0) red[6 + wv] = sq;
        __syncthreads();
        float var = (red[6 + half * 3] + red[6 + half * 3 + 1] + red[6 + half * 3 + 2]) * (1.f / 384.f);
        float inv = rsqrtf(var + 1e-5f);

        g_s[p * DINNER + tc]       = (d0 * inv * g0c + b0c) * gz[pos * DINNER + tc];
        g_s[p * DINNER + tc + 192] = (d1 * inv * g1c + b1c) * gz[pos * DINNER + tc + 192];
    }
    __syncthreads();

    float acc[4] = {0.f, 0.f, 0.f, 0.f};
    const int pbase = half * 4;
    for (int dd = 0; dd < DINNER; dd += 4) {
        float w0 = W_out[(dd + 0) * DMODEL + tc];
        float w1 = W_out[(dd + 1) * DMODEL + tc];
        float w2 = W_out[(dd + 2) * DMODEL + tc];
        float w3 = W_out[(dd + 3) * DMODEL + tc];
#pragma unroll
        for (int i = 0; i < 4; ++i) {
            const float4 g = *(const float4*)&g_s[(pbase + i) * DINNER + dd];
            acc[i] += g.x * w0 + g.y * w1 + g.z * w2 + g.w * w3;
        }
    }
#pragma unroll
    for (int i = 0; i < 4; ++i) out[(pos0 + pbase + i) * DMODEL + tc] = acc[i];
}

// ---------------------------------------------------------------------------
extern "C" void kernel_launch(void* const* d_in, const int* in_sizes, int n_in,
                              void* d_out, int out_size, void* d_ws, size_t ws_size,
                              hipStream_t stream) {
    (void)in_sizes; (void)n_in; (void)out_size; (void)ws_size;
    const float* x      = (const float*)d_in[0];
    const float* W_in   = (const float*)d_in[1];
    const float* conv_w = (const float*)d_in[2];
    const float* conv_b = (const float*)d_in[3];
    const float* W_x    = (const float*)d_in[4];
    const float* W_dt   = (const float*)d_in[5];
    const float* b_dt   = (const float*)d_in[6];
    const float* A_log  = (const float*)d_in[7];
    const float* Dp     = (const float*)d_in[8];
    const float* W_out  = (const float*)d_in[9];
    const float* gamma  = (const float*)d_in[10];
    const float* beta   = (const float*)d_in[11];

    // ws layout (27.75 MB, verified):
    //  x_val fp32 : 6 MB    @ 0
    //  u     fp16 : 3 MB    @ 6291456
    //  xd    fp32 : 0.75 MB @ 9437184   (B/C interleaved layout, k3-private)
    //  dt32  fp32 : 6 MB    @ 10223616
    //  gz    fp32 : 6 MB    @ 16515072
    //  y_acc fp32 : 6 MB    @ 22806528  (SEPARATE from x_val: no halo race)
    char* base = (char*)d_ws;
    float*  x_val = (float*)base;
    __half* u     = (__half*)(base + 6291456);
    float*  xd    = (float*)(base + 9437184);
    float*  dt32  = (float*)(base + 10223616);
    float*  gz    = (float*)(base + 16515072);
    float*  y_acc = (float*)(base + 22806528);

    hipLaunchKernelGGL(k1_inproj, dim3(NPOS / 8 * 3), dim3(256), 0, stream, x, W_in, x_val, gz);
    hipLaunchKernelGGL(k2_conv_dt, dim3(NPOS), dim3(384), 0, stream,
                       x_val, conv_w, conv_b, W_x, W_dt, b_dt, Dp, u, xd, dt32, y_acc);
    hipLaunchKernelGGL(k3_scan, dim3(384), dim3(256), 0, stream,
                       u, xd, dt32, A_log, y_acc);
    hipLaunchKernelGGL(k4_out, dim3(NPOS / 8), dim3(384), 0, stream,
                       y_acc, gz, gamma, beta, W_out, (float*)d_out);
}